// Round 5
// baseline (10094.247 us; speedup 1.0000x reference)
//
#include <hip/hip_runtime.h>
#include <hip/hip_fp16.h>
#include <cstdint>
#include <cstddef>

typedef _Float16 f16;
typedef _Float16 f16x8 __attribute__((ext_vector_type(8)));
typedef _Float16 f16x4 __attribute__((ext_vector_type(4)));
typedef float    f32x4 __attribute__((ext_vector_type(4)));

// ---------------- ws layout (bytes) ----------------
// Gs   f32 [2048][10]                :      0 ..  81920
// QM   f32 [10][16]                  :  81920 ..  82560
// CB   f32 [10][16]                  :  82560 ..  83200
// W1T  f16 [16][5][4][80]            :  83200 .. 134400   (dead after k1)
//   A9  f16 [57][64][4]  (overlay)   :  83200 .. 112384   (written after k1)
// WhhP f16 [57*10][64][8]            : 134400 .. 718080
// giP  f16 [2048][57][64][4]         : 718080 .. 60486912
#define WS_GS    0u
#define WS_QM    81920u
#define WS_CB    82560u
#define WS_W1T   83200u
#define WS_A9    83200u
#define WS_WHHP  134400u
#define WS_GIP   718080u

__device__ __forceinline__ float sigm_(float x){ return 1.0f/(1.0f + __expf(-x)); }
__device__ __forceinline__ float tanh_(float x){
  float ax = fabsf(x);
  float e  = __expf(-2.0f*ax);
  float r  = (1.0f - e)/(1.0f + e);
  return x < 0.0f ? -r : r;
}
__device__ __forceinline__ int imin_(int a,int b){ return a<b?a:b; }

// ================= K0: prep (QM, CB, W1T) =================
__global__ __launch_bounds__(512) void k0_prep(
    const float* __restrict__ q, const float* __restrict__ m,
    const float* __restrict__ W1, const float* __restrict__ b1,
    float* __restrict__ QM, float* __restrict__ CBo, f16* __restrict__ W1T)
{
  int tid = threadIdx.x;
  if (tid < 160){
    int k = tid >> 4, h = tid & 15;
    float acc = 0.f;
    for (int d = 0; d < 300; ++d)
      acc += q[k*300+d]*W1[(2100+d)*16+h] + m[k*300+d]*W1[(2400+d)*16+h];
    QM[tid] = acc;
  } else if (tid < 320){
    int b = (tid-160) >> 4, h = tid & 15;
    float acc = b1[h];
    for (int d = 0; d < 300; ++d)
      acc += m[b*300+d]*W1[(300+d)*16+h] + q[b*300+d]*W1[(600+d)*16+h];
    CBo[tid-160] = acc;
  }
  const int blkoff[5] = {0, 900, 1200, 1500, 1800};
  for (int i = tid; i < 25600; i += 512){
    int ii = i % 80; int r = i / 80;
    int dg = r % 4; r /= 4;
    int blk = r % 5; int h = r / 5;
    int d = dg*80 + ii;
    float v = 0.f;
    if (d < 300) v = W1[(blkoff[blk]+d)*16 + h];
    W1T[i] = (f16)v;
  }
}

// ================= Kpack: Whh -> MFMA A-fragment layout (f16) =================
__global__ __launch_bounds__(64) void k_pack(const float* __restrict__ Whh, f16* __restrict__ WhhP)
{
  int bid = blockIdx.x, l = threadIdx.x;
  int mt = bid / 10, kc = bid % 10;
  int gate = mt / 19, cb = mt % 19;
  int rr = l & 15, grp = l >> 4;
  int c = cb*16 + rr;
  int j = gate*300 + imin_(c, 299);
  f16x8 v;
  #pragma unroll
  for (int e = 0; e < 8; ++e){
    int d = kc*32 + grp*8 + e;
    float x = Whh[(size_t)imin_(d,299)*900 + j];
    v[e] = (f16)((d < 300 && c < 300) ? x : 0.f);
  }
  *(f16x8*)&WhhP[((size_t)bid*64 + l)*8] = v;
}

// ================= Kpack9: kc9 as K=16 A-frag, with bhh_n bias row at k-slot 300 =================
// A9[mt][l][e]: row = l&15 -> c = cb*16+row; k = 288 + (l>>4)*4 + e.
// k==300 && gate==2 -> bhh[600+c] (bias trick; B9 has a constant 1.0 in that slot).
__global__ __launch_bounds__(64) void k_pack9(const float* __restrict__ Whh,
                                              const float* __restrict__ bhh,
                                              f16* __restrict__ A9)
{
  int mt = blockIdx.x, l = threadIdx.x;
  int gate = mt / 19, cb = mt % 19;
  int row = l & 15, grp = l >> 4;
  int c = cb*16 + row;
  f16x4 v;
  #pragma unroll
  for (int e = 0; e < 4; ++e){
    int d = 288 + grp*4 + e;
    float x = 0.f;
    if (c < 300){
      if (d < 300) x = Whh[(size_t)d*900 + gate*300 + c];
      else if (d == 300 && gate == 2) x = bhh[600 + c];
    }
    v[e] = (f16)x;
  }
  *(f16x4*)&A9[((size_t)mt*64 + l)*4] = v;
}

// ================= K1: attention gate -> G[b][t] (d_out[0:20480]) =================
__global__ __launch_bounds__(512) void k1_attn(
    const float* __restrict__ cs, const float* __restrict__ mI, const float* __restrict__ qI,
    const float* __restrict__ mask, const float* __restrict__ Wb,
    const float* __restrict__ W2, const float* __restrict__ b2,
    const float* __restrict__ QMg, const float* __restrict__ CBg, const f16* __restrict__ W1Tg,
    float* __restrict__ Gout)
{
  __shared__ __align__(16) float q_s[3000];
  __shared__ __align__(16) float m_s[3000];
  __shared__ float Wb_s[3000];
  __shared__ float QM_s[160], CB_s[160], W2_s[16];
  __shared__ __align__(16) f16 W1T_s[25600];
  __shared__ float cwb_s[8][10][10];
  int tid = threadIdx.x;
  for (int i = tid; i < 3000; i += 512){ q_s[i] = qI[i]; m_s[i] = mI[i]; Wb_s[i] = Wb[i]; }
  for (int i = tid; i < 160; i += 512){ QM_s[i] = QMg[i]; CB_s[i] = CBg[i]; }
  if (tid < 16) W2_s[tid] = W2[tid];
  for (int i = tid; i < 25600; i += 512) W1T_s[i] = W1Tg[i];
  __syncthreads();

  int w = tid >> 6, l = tid & 63, dg = l >> 4, lo = l & 15;
  int t = blockIdx.x*8 + w;
  float a[10], cwb[10];
  #pragma unroll
  for (int b = 0; b < 10; ++b){ a[b] = 0.f; cwb[b] = 0.f; }

  for (int i = 0; i < 10; ++i){
    int d0 = dg*80 + i*8;
    const int wbase = lo*1600 + dg*80 + i*8;
    f16x8 wf0 = *(const f16x8*)&W1T_s[wbase + 0*320];
    f16x8 wf1 = *(const f16x8*)&W1T_s[wbase + 1*320];
    f16x8 wf2 = *(const f16x8*)&W1T_s[wbase + 2*320];
    f16x8 wf3 = *(const f16x8*)&W1T_s[wbase + 3*320];
    f16x8 wf4 = *(const f16x8*)&W1T_s[wbase + 4*320];
    int dc0 = imin_(d0, 296), dc1 = imin_(d0 + 4, 296);
    #pragma unroll
    for (int b = 0; b < 10; ++b){
      const float* csb = cs + ((size_t)t*10 + b)*300;
      float4 c0 = *(const float4*)(csb + dc0);
      float4 c1 = *(const float4*)(csb + dc1);
      float4 q0 = *(const float4*)(q_s + b*300 + dc0);
      float4 q1 = *(const float4*)(q_s + b*300 + dc1);
      float4 m0 = *(const float4*)(m_s + b*300 + dc0);
      float4 m1 = *(const float4*)(m_s + b*300 + dc1);
      float cv[8] = {c0.x,c0.y,c0.z,c0.w,c1.x,c1.y,c1.z,c1.w};
      float qv[8] = {q0.x,q0.y,q0.z,q0.w,q1.x,q1.y,q1.z,q1.w};
      float mv[8] = {m0.x,m0.y,m0.z,m0.w,m1.x,m1.y,m1.z,m1.w};
      #pragma unroll
      for (int e = 0; e < 8; ++e){
        int d = d0 + e;
        float cvv = cv[e];
        a[b] += cvv*(float)wf0[e] + (cvv*qv[e])*(float)wf1[e] + (cvv*mv[e])*(float)wf2[e]
              + fabsf(cvv - qv[e])*(float)wf3[e] + fabsf(cvv - mv[e])*(float)wf4[e];
        float wv = Wb_s[imin_(d, 299)*10 + imin_(lo, 9)];
        wv = (lo < 10 && d < 300) ? wv : 0.f;
        cwb[b] += cvv*wv;
      }
    }
  }
  #pragma unroll
  for (int b = 0; b < 10; ++b){
    float v = cwb[b];
    v += __shfl_xor(v, 16, 64);
    v += __shfl_xor(v, 32, 64);
    cwb[b] = v;
  }
  if (dg == 0 && lo < 10){
    #pragma unroll
    for (int b = 0; b < 10; ++b) cwb_s[w][b][lo] = cwb[b];
  }
  __asm__ volatile("s_waitcnt lgkmcnt(0)" ::: "memory");
  __builtin_amdgcn_sched_barrier(0);
  float b2v = b2[0];
  #pragma unroll
  for (int b = 0; b < 10; ++b){
    float cross = 0.f;
    #pragma unroll
    for (int k = 0; k < 10; ++k) cross += cwb_s[w][b][k]*QM_s[k*16 + lo];
    float v = a[b];
    v += __shfl_xor(v, 16, 64);
    v += __shfl_xor(v, 32, 64);
    v += CB_s[b*16 + lo] + cross;
    float tv = tanh_(v)*W2_s[lo];
    tv += __shfl_xor(tv, 1, 64);
    tv += __shfl_xor(tv, 2, 64);
    tv += __shfl_xor(tv, 4, 64);
    tv += __shfl_xor(tv, 8, 64);
    a[b] = sigm_(tv + b2v);
  }
  if (l == 0){
    #pragma unroll
    for (int b = 0; b < 10; ++b) Gout[b*2048 + t] = a[b]*mask[t*10 + b];
  }
}

// ================= K2: softmax over T per b: Gs[t][b] =================
__global__ __launch_bounds__(256) void k2_softmax(const float* __restrict__ G, float* __restrict__ Gs)
{
  int b = blockIdx.x, tid = threadIdx.x;
  __shared__ float red[4];
  float v[8];
  #pragma unroll
  for (int k = 0; k < 8; ++k) v[k] = G[b*2048 + tid + k*256];
  float mx = v[0];
  #pragma unroll
  for (int k = 1; k < 8; ++k) mx = fmaxf(mx, v[k]);
  #pragma unroll
  for (int off = 1; off < 64; off <<= 1) mx = fmaxf(mx, __shfl_xor(mx, off, 64));
  if ((tid & 63) == 0) red[tid >> 6] = mx;
  __syncthreads();
  mx = fmaxf(fmaxf(red[0], red[1]), fmaxf(red[2], red[3]));
  __syncthreads();
  float e[8], s = 0.f;
  #pragma unroll
  for (int k = 0; k < 8; ++k){ e[k] = __expf(v[k]-mx); s += e[k]; }
  #pragma unroll
  for (int off = 1; off < 64; off <<= 1) s += __shfl_xor(s, off, 64);
  if ((tid & 63) == 0) red[tid >> 6] = s;
  __syncthreads();
  s = red[0]+red[1]+red[2]+red[3];
  float inv = 1.0f / s;
  #pragma unroll
  for (int k = 0; k < 8; ++k) Gs[(tid + k*256)*10 + b] = e[k]*inv;
}

// ================= K3: gi[t] = seq[t] @ Wih + bih (+bhh folded for r,z) =================
__global__ __launch_bounds__(256) void k3_gi(
    const float* __restrict__ cs, const float* __restrict__ Gs,
    const float* __restrict__ Wih, const float* __restrict__ bih, const float* __restrict__ bhh,
    f16* __restrict__ giP)
{
  int t = blockIdx.x, tid = threadIdx.x;
  __shared__ __align__(16) float sfT[300*16];
  for (int i = tid; i < 3000; i += 256){
    int d = i / 10, bcol = i % 10;
    int jj = d % 10;
    sfT[d*16 + bcol] = Gs[t*10 + jj] * cs[((size_t)t*10 + jj)*300 + bcol*30 + d/10];
  }
  __syncthreads();
  float acc[4][10];
  #pragma unroll
  for (int jp = 0; jp < 4; ++jp)
    #pragma unroll
    for (int b = 0; b < 10; ++b) acc[jp][b] = 0.f;
  for (int d = 0; d < 300; ++d){
    float4 s0 = *(const float4*)&sfT[d*16 + 0];
    float4 s1 = *(const float4*)&sfT[d*16 + 4];
    float4 s2 = *(const float4*)&sfT[d*16 + 8];
    float sb[10] = {s0.x,s0.y,s0.z,s0.w, s1.x,s1.y,s1.z,s1.w, s2.x,s2.y};
    #pragma unroll
    for (int jp = 0; jp < 4; ++jp){
      int j = jp*256 + tid;
      float wv = Wih[(size_t)d*900 + imin_(j, 899)];
      wv = (j < 900) ? wv : 0.f;
      #pragma unroll
      for (int b = 0; b < 10; ++b) acc[jp][b] += wv * sb[b];
    }
  }
  #pragma unroll
  for (int jp = 0; jp < 4; ++jp){
    int j = jp*256 + tid;
    if (j < 900){
      int gate = j / 300, c = j - gate*300;
      int cb = c >> 4, rr = c & 15;
      int mt = gate*19 + cb, g = rr >> 2, er = rr & 3;
      float bias = bih[j] + (j < 600 ? bhh[j] : 0.f);
      size_t base = ((size_t)t*57 + mt)*256;
      #pragma unroll
      for (int b = 0; b < 10; ++b)
        giP[base + (size_t)(((g<<4)|b)*4 + er)] = (f16)(acc[jp][b] + bias);
    }
  }
}

// ================= K4: sequential GRU, SINGLE workgroup, Whh resident in VGPR+LDS =================
// 8 waves; wave w owns cb-units (all 3 gates -> combine is wave-local):
//   w<3: cb {3w..3w+2} (9 tiles); w>=3: cb {9+2(w-3), +1} (6 tiles).
// Per tile (K=320): kc0..NV-1 in VGPR, kc NV..6 in LDS, kc7/kc8 streamed from L2
// each step (register-reused batches), kc9 as K=16 MFMA streamed (A9, with bhh_n
// bias row at k-slot 300 against a constant-1.0 in B9).
// h exchange: LDS ping-pong B buffers + one __syncthreads per step. No atomics.
#define BPAR 4864   // f16 per parity: 9*512 + 256

template<int NCB>
__device__ __forceinline__ void gru_body(
    int w, int l, const f16* __restrict__ WhhP, const f16* __restrict__ A9g,
    const f16* __restrict__ giP, const float* __restrict__ mI,
    float* __restrict__ hout, f16* A_lds, f16* Bb)
{
  constexpr int T  = 3*NCB;
  constexpr int NV = (NCB == 3) ? 3 : 6;   // kc count in VGPR
  constexpr int NL = 7 - NV;               // kc count in LDS
  const int cb0 = (NCB == 3) ? w*3 : 9 + (w-3)*2;
  const int bl = l & 15, g = l >> 4;
  const int slot0 = (NCB == 3) ? w*36 : 108 + (w-3)*6;

  // ---- prologue: resident A frags + LDS A frags ----
  f16x8 aV[T][NV];
  #pragma unroll
  for (int gate = 0; gate < 3; ++gate){
    #pragma unroll
    for (int u = 0; u < NCB; ++u){
      const int ti = gate*NCB + u;
      const int mt = gate*19 + cb0 + u;
      #pragma unroll
      for (int kc = 0; kc < NV; ++kc)
        aV[ti][kc] = *(const f16x8*)&WhhP[(size_t)((mt*10+kc)*64 + l)*8];
      #pragma unroll
      for (int j = 0; j < NL; ++j){
        f16x8 v = *(const f16x8*)&WhhP[(size_t)((mt*10+NV+j)*64 + l)*8];
        *(f16x8*)&A_lds[(size_t)((slot0 + ti*NL + j)*64 + l)*8] = v;
      }
    }
  }

  // ---- h0 (f32 master in regs) + publish into parity 0 ----
  float hreg[NCB][4];
  #pragma unroll
  for (int u = 0; u < NCB; ++u){
    const int c0 = (cb0+u)*16 + g*4;
    #pragma unroll
    for (int rg = 0; rg < 4; ++rg){
      int c = c0 + rg;
      hreg[u][rg] = (bl < 10 && c < 300) ? mI[bl*300 + imin_(c,299)] : 0.f;
    }
  }
  #pragma unroll
  for (int u = 0; u < NCB; ++u){
    const int c0 = (cb0+u)*16 + g*4;
    if (bl < 10 && c0 < 300){
      f16x4 pv = {(f16)hreg[u][0], (f16)hreg[u][1], (f16)hreg[u][2], (f16)hreg[u][3]};
      if (c0 >= 288) *(f16x4*)&Bb[4608 + l*4] = pv;
      else {
        int kc = c0 >> 5, grp = (c0 & 31) >> 3, e0 = c0 & 7;
        *(f16x4*)&Bb[kc*512 + (grp*16 + bl)*8 + e0] = pv;
      }
    }
  }
  __syncthreads();

  for (int t = 0; t < 2048; ++t){
    __asm__ volatile("" ::: "memory");   // defeat cross-iteration load hoisting
    const int cur = t & 1;
    const f16* Bc = Bb + cur*BPAR;
    f16* Bn = Bb + (cur^1)*BPAR;

    // gi loads (early; consumed at combine)
    f16x4 gv[3][NCB];
    const f16* gp = giP + (size_t)t*57*256;
    #pragma unroll
    for (int gate = 0; gate < 3; ++gate)
      #pragma unroll
      for (int u = 0; u < NCB; ++u)
        gv[gate][u] = *(const f16x4*)&gp[(size_t)((gate*19+cb0+u)*64 + l)*4];

    // streamed A: kc9 (K16) + kc7 issued now; kc8 reuses sS after kc7 consumed
    f16x4 s9[T];
    f16x8 sS[T];
    #pragma unroll
    for (int gate = 0; gate < 3; ++gate)
      #pragma unroll
      for (int u = 0; u < NCB; ++u){
        const int ti = gate*NCB + u, mt = gate*19 + cb0 + u;
        s9[ti] = *(const f16x4*)&A9g[(size_t)(mt*64 + l)*4];
        sS[ti] = *(const f16x8*)&WhhP[(size_t)((mt*10+7)*64 + l)*8];
      }

    f32x4 acc[3][NCB];
    #pragma unroll
    for (int gate = 0; gate < 3; ++gate)
      #pragma unroll
      for (int u = 0; u < NCB; ++u) acc[gate][u] = (f32x4){0.f,0.f,0.f,0.f};

    // V phase
    #pragma unroll
    for (int kc = 0; kc < NV; ++kc){
      f16x8 bk = *(const f16x8*)&Bc[kc*512 + l*8];
      #pragma unroll
      for (int gate = 0; gate < 3; ++gate)
        #pragma unroll
        for (int u = 0; u < NCB; ++u)
          acc[gate][u] = __builtin_amdgcn_mfma_f32_16x16x32_f16(aV[gate*NCB+u][kc], bk, acc[gate][u], 0,0,0);
    }
    // L phase
    #pragma unroll
    for (int j = 0; j < NL; ++j){
      f16x8 bk = *(const f16x8*)&Bc[(NV+j)*512 + l*8];
      #pragma unroll
      for (int gate = 0; gate < 3; ++gate)
        #pragma unroll
        for (int u = 0; u < NCB; ++u){
          const int ti = gate*NCB + u;
          f16x8 a = *(const f16x8*)&A_lds[(size_t)((slot0 + ti*NL + j)*64 + l)*8];
          acc[gate][u] = __builtin_amdgcn_mfma_f32_16x16x32_f16(a, bk, acc[gate][u], 0,0,0);
        }
    }
    // kc7 consume
    {
      f16x8 bk = *(const f16x8*)&Bc[7*512 + l*8];
      #pragma unroll
      for (int gate = 0; gate < 3; ++gate)
        #pragma unroll
        for (int u = 0; u < NCB; ++u)
          acc[gate][u] = __builtin_amdgcn_mfma_f32_16x16x32_f16(sS[gate*NCB+u], bk, acc[gate][u], 0,0,0);
    }
    // kc8: reuse sS registers (WAR dependency serializes issue after kc7 use)
    #pragma unroll
    for (int gate = 0; gate < 3; ++gate)
      #pragma unroll
      for (int u = 0; u < NCB; ++u){
        const int mt = gate*19 + cb0 + u;
        sS[gate*NCB+u] = *(const f16x8*)&WhhP[(size_t)((mt*10+8)*64 + l)*8];
      }
    {
      f16x8 bk = *(const f16x8*)&Bc[8*512 + l*8];
      #pragma unroll
      for (int gate = 0; gate < 3; ++gate)
        #pragma unroll
        for (int u = 0; u < NCB; ++u)
          acc[gate][u] = __builtin_amdgcn_mfma_f32_16x16x32_f16(sS[gate*NCB+u], bk, acc[gate][u], 0,0,0);
    }
    // kc9 (K=16, includes bhh_n bias via constant-1 slot)
    {
      f16x4 b9 = *(const f16x4*)&Bc[4608 + l*4];
      #pragma unroll
      for (int gate = 0; gate < 3; ++gate)
        #pragma unroll
        for (int u = 0; u < NCB; ++u)
          acc[gate][u] = __builtin_amdgcn_mfma_f32_16x16x16f16(s9[gate*NCB+u], b9, acc[gate][u], 0,0,0);
    }

    // combine (wave-local r,z,n trio) + publish h_{t+1}
    #pragma unroll
    for (int u = 0; u < NCB; ++u){
      const int c0 = (cb0+u)*16 + g*4;
      if (bl < 10 && c0 < 300){
        f16 hx[4];
        #pragma unroll
        for (int rg = 0; rg < 4; ++rg){
          float r  = sigm_(acc[0][u][rg] + (float)gv[0][u][rg]);
          float z  = sigm_(acc[1][u][rg] + (float)gv[1][u][rg]);
          float n  = tanh_((float)gv[2][u][rg] + r*acc[2][u][rg]);
          float hn = (1.f - z)*n + z*hreg[u][rg];
          hreg[u][rg] = hn;
          hx[rg] = (f16)hn;
        }
        f16x4 pv = {hx[0], hx[1], hx[2], hx[3]};
        if (c0 >= 288) *(f16x4*)&Bn[4608 + l*4] = pv;
        else {
          int kc = c0 >> 5, grp = (c0 & 31) >> 3, e0 = c0 & 7;
          *(f16x4*)&Bn[kc*512 + (grp*16 + bl)*8 + e0] = pv;
        }
      }
    }
    __syncthreads();
  }

  // final h (exact f32 master)
  #pragma unroll
  for (int u = 0; u < NCB; ++u){
    const int c0 = (cb0+u)*16 + g*4;
    if (bl < 10 && c0 < 300){
      #pragma unroll
      for (int rg = 0; rg < 4; ++rg)
        hout[bl*300 + c0 + rg] = hreg[u][rg];
    }
  }
}

__global__ __launch_bounds__(512, 2) void k4_single(
    const f16* __restrict__ WhhP, const f16* __restrict__ A9g,
    const f16* __restrict__ giP, const float* __restrict__ mI,
    float* __restrict__ hout)
{
  __shared__ __align__(16) f16 A_lds[138*512];   // 141312 B
  __shared__ __align__(16) f16 Bb[2*BPAR];       //  19456 B
  const int tid = threadIdx.x;
  const int w = tid >> 6, l = tid & 63;

  // zero both B parities (col pads / k pads must be 0)
  uint32_t* bz = (uint32_t*)Bb;
  for (int i = tid; i < 2*BPAR/2; i += 512) bz[i] = 0u;
  __syncthreads();
  // constant 1.0 at k-slot 300 of B9 (lane 48..63, e=0), both parities
  if (tid < 32){
    int p = tid >> 4, ll = 48 + (tid & 15);
    bz[p*(BPAR/2) + (9216 + ll*8)/4] = 0x00003C00u;  // f16 {1.0, 0.0}
  }

  if (w < 3) gru_body<3>(w, l, WhhP, A9g, giP, mI, hout, A_lds, Bb);
  else       gru_body<2>(w, l, WhhP, A9g, giP, mI, hout, A_lds, Bb);
}

// ================= launch =================
extern "C" void kernel_launch(void* const* d_in, const int* in_sizes, int n_in,
                              void* d_out, int out_size, void* d_ws, size_t ws_size,
                              hipStream_t stream)
{
  const float* cs   = (const float*)d_in[0];
  const float* m    = (const float*)d_in[1];
  const float* q    = (const float*)d_in[2];
  const float* mask = (const float*)d_in[3];
  const float* Wb   = (const float*)d_in[4];
  const float* W1   = (const float*)d_in[5];
  const float* b1   = (const float*)d_in[6];
  const float* W2   = (const float*)d_in[7];
  const float* b2   = (const float*)d_in[8];
  const float* Wih  = (const float*)d_in[9];
  const float* Whh  = (const float*)d_in[10];
  const float* bih  = (const float*)d_in[11];
  const float* bhh  = (const float*)d_in[12];
  float* out = (float*)d_out;
  char* ws = (char*)d_ws;
  float* Gs   = (float*)(ws + WS_GS);
  float* QM   = (float*)(ws + WS_QM);
  float* CB   = (float*)(ws + WS_CB);
  f16*   W1T  = (f16*)(ws + WS_W1T);
  f16*   A9   = (f16*)(ws + WS_A9);     // overlays W1T (dead after k1)
  f16*   WhhP = (f16*)(ws + WS_WHHP);
  f16*   giP  = (f16*)(ws + WS_GIP);

  k0_prep<<<dim3(1), dim3(512), 0, stream>>>(q, m, W1, b1, QM, CB, W1T);
  k_pack<<<dim3(570), dim3(64), 0, stream>>>(Whh, WhhP);
  k1_attn<<<dim3(256), dim3(512), 0, stream>>>(cs, m, q, mask, Wb, W2, b2, QM, CB, W1T, out);
  k2_softmax<<<dim3(10), dim3(256), 0, stream>>>(out, Gs);
  k3_gi<<<dim3(2048), dim3(256), 0, stream>>>(cs, Gs, Wih, bih, bhh, giP);
  k_pack9<<<dim3(57), dim3(64), 0, stream>>>(Whh, bhh, A9);
  k4_single<<<dim3(1), dim3(512), 0, stream>>>(WhhP, A9, giP, m, out + 20480);
}